// Round 1
// baseline (487.725 us; speedup 1.0000x reference)
//
#include <hip/hip_runtime.h>

// StructuralGcn: 3-layer GCN over N=50000 nodes, E=800000 edges (+self loops).
// Strategy: per layer: g = (x@W)*dinv  ->  atomic scatter acc[dst]+=g[src]
//           -> z = relu(dinv*(acc + g_self) + b)   (self loop folded in).

#define IN_C 128

// ---------------- degree / dinv ----------------

__global__ void deg_count_kernel(const int* __restrict__ dst, float* __restrict__ deg,
                                 int n_edges) {
    const int stride = gridDim.x * blockDim.x;
    for (int e = blockIdx.x * blockDim.x + threadIdx.x; e < n_edges; e += stride)
        atomicAdd(&deg[dst[e]], 1.0f);
}

__global__ void dinv_kernel(float* __restrict__ deg, int n) {
    const int i = blockIdx.x * blockDim.x + threadIdx.x;
    if (i < n) deg[i] = rsqrtf(deg[i] + 1.0f);   // +1 = self loop; deg+1 > 0 always
}

// ---------------- GEMM with dinv-scaled epilogue ----------------
// g[i][c] = (sum_k x[i][k] * W[k][c]) * dinv[i]
// Block = 256 threads handles NPB=64 nodes. Thread owns column c = tid % COUT
// and NPB*COUT/256 nodes. W column lives in registers (loads are coalesced
// across the COUT-lane group); x rows are broadcast float4 loads.

template <int KDIM, int COUT>
__global__ __launch_bounds__(256) void gemm_scale_kernel(
    const float* __restrict__ x, const float* __restrict__ W,
    const float* __restrict__ dinv, float* __restrict__ g, int n_nodes) {
    constexpr int NPB = 64;
    constexpr int GROUPS = 256 / COUT;   // 4 (COUT=64) or 8 (COUT=32)
    constexpr int NPT = NPB / GROUPS;    // 16 or 8 nodes per thread

    const int tid = threadIdx.x;
    const int c = tid % COUT;
    const int grp = tid / COUT;
    const int base = blockIdx.x * NPB;

    float wreg[KDIM];
#pragma unroll
    for (int k = 0; k < KDIM; ++k) wreg[k] = W[k * COUT + c];

    for (int nn = 0; nn < NPT; ++nn) {
        const int node = base + grp + nn * GROUPS;
        if (node >= n_nodes) break;
        const float4* xr = (const float4*)(x + (size_t)node * KDIM);
        float acc = 0.0f;
#pragma unroll
        for (int k4 = 0; k4 < KDIM / 4; ++k4) {
            const float4 xv = xr[k4];
            acc += xv.x * wreg[4 * k4 + 0] + xv.y * wreg[4 * k4 + 1] +
                   xv.z * wreg[4 * k4 + 2] + xv.w * wreg[4 * k4 + 3];
        }
        g[(size_t)node * COUT + c] = acc * dinv[node];
    }
}

// Layer 3: COUT = 1 — plain dot product per node.
__global__ void gemm3_kernel(const float* __restrict__ z2, const float* __restrict__ W3,
                             const float* __restrict__ dinv, float* __restrict__ g3, int n) {
    const int i = blockIdx.x * blockDim.x + threadIdx.x;
    if (i >= n) return;
    const float4* xr = (const float4*)(z2 + (size_t)i * 32);
    float acc = 0.0f;
#pragma unroll
    for (int k4 = 0; k4 < 8; ++k4) {
        const float4 xv = xr[k4];
        acc += xv.x * W3[4 * k4 + 0] + xv.y * W3[4 * k4 + 1] +
               xv.z * W3[4 * k4 + 2] + xv.w * W3[4 * k4 + 3];
    }
    g3[i] = acc * dinv[i];
}

// ---------------- edge scatter: acc[dst][c] += g[src][c] ----------------
// C = 1<<LOGC channels. Thread t -> edge t>>LOGC, channel t&(C-1): the gather
// reads one contiguous C-float row per 64/C edges and the atomics hit C
// consecutive addresses -> coalesced bursts.

template <int LOGC>
__global__ void scatter_kernel(const int* __restrict__ src, const int* __restrict__ dst,
                               const float* __restrict__ g, float* __restrict__ acc,
                               int n_edges) {
    const long long total = (long long)n_edges << LOGC;
    const long long stride = (long long)gridDim.x * blockDim.x;
    for (long long t = (long long)blockIdx.x * blockDim.x + threadIdx.x; t < total;
         t += stride) {
        const int e = (int)(t >> LOGC);
        const int c = (int)(t & ((1 << LOGC) - 1));
        const int s = src[e];
        const int d = dst[e];
        atomicAdd(acc + (((size_t)d) << LOGC) + c, g[(((size_t)s) << LOGC) + c]);
    }
}

// ---------------- finalize: z = [relu](dinv*(acc + g_self) + b), in place ----

template <int LOGC, bool RELU>
__global__ void finalize_kernel(float* __restrict__ acc, const float* __restrict__ g,
                                const float* __restrict__ dinv, const float* __restrict__ b,
                                int n_nodes) {
    const int t = blockIdx.x * blockDim.x + threadIdx.x;
    if (t >= (n_nodes << LOGC)) return;
    const int i = t >> LOGC;
    const int c = t & ((1 << LOGC) - 1);
    const float v = dinv[i] * (acc[t] + g[t]) + b[c];
    acc[t] = RELU ? fmaxf(v, 0.0f) : v;
}

__global__ void finalize3_kernel(const float* __restrict__ acc3, const float* __restrict__ g3,
                                 const float* __restrict__ dinv, const float* __restrict__ b3,
                                 float* __restrict__ out, int n) {
    const int i = blockIdx.x * blockDim.x + threadIdx.x;
    if (i < n) out[i] = dinv[i] * (acc3[i] + g3[i]) + b3[0];
}

// ---------------- launcher ----------------

extern "C" void kernel_launch(void* const* d_in, const int* in_sizes, int n_in,
                              void* d_out, int out_size, void* d_ws, size_t ws_size,
                              hipStream_t stream) {
    const float* x  = (const float*)d_in[0];
    const int*   ei = (const int*)d_in[1];
    const float* W1 = (const float*)d_in[2];
    const float* b1 = (const float*)d_in[3];
    const float* W2 = (const float*)d_in[4];
    const float* b2 = (const float*)d_in[5];
    const float* W3 = (const float*)d_in[6];
    const float* b3 = (const float*)d_in[7];
    float* out = (float*)d_out;

    const int n_nodes = in_sizes[0] / IN_C;    // 50000
    const int n_edges = in_sizes[1] / 2;       // 800000
    const int* src = ei;                       // edge_index[0]
    const int* dst = ei + n_edges;             // edge_index[1]

    auto align_up = [](size_t v) { return (v + 255) & ~(size_t)255; };
    char* p = (char*)d_ws;
    float* dinv = (float*)p; p += align_up((size_t)n_nodes * 4);        // deg -> dinv
    float* g1   = (float*)p; p += align_up((size_t)n_nodes * 64 * 4);
    float* acc1 = (float*)p; p += align_up((size_t)n_nodes * 64 * 4);   // -> z1 in place
    float* g2   = (float*)p; p += align_up((size_t)n_nodes * 32 * 4);
    float* acc2 = (float*)p; p += align_up((size_t)n_nodes * 32 * 4);   // -> z2 in place
    float* g3   = (float*)p; p += align_up((size_t)n_nodes * 4);
    float* acc3 = (float*)p; p += align_up((size_t)n_nodes * 4);
    (void)ws_size; (void)n_in; (void)out_size;

    // zero the accumulators (ws is poisoned, not re-zeroed between replays)
    hipMemsetAsync(dinv, 0, (size_t)n_nodes * 4, stream);
    hipMemsetAsync(acc1, 0, (size_t)n_nodes * 64 * 4, stream);
    hipMemsetAsync(acc2, 0, (size_t)n_nodes * 32 * 4, stream);
    hipMemsetAsync(acc3, 0, (size_t)n_nodes * 4, stream);

    // degree + normalization
    deg_count_kernel<<<2048, 256, 0, stream>>>(dst, dinv, n_edges);
    dinv_kernel<<<(n_nodes + 255) / 256, 256, 0, stream>>>(dinv, n_nodes);

    // layer 1: 128 -> 64, relu
    gemm_scale_kernel<128, 64><<<(n_nodes + 63) / 64, 256, 0, stream>>>(x, W1, dinv, g1, n_nodes);
    scatter_kernel<6><<<4096, 256, 0, stream>>>(src, dst, g1, acc1, n_edges);
    finalize_kernel<6, true><<<((n_nodes << 6) + 255) / 256, 256, 0, stream>>>(acc1, g1, dinv, b1, n_nodes);

    // layer 2: 64 -> 32, relu
    gemm_scale_kernel<64, 32><<<(n_nodes + 63) / 64, 256, 0, stream>>>(acc1, W2, dinv, g2, n_nodes);
    scatter_kernel<5><<<4096, 256, 0, stream>>>(src, dst, g2, acc2, n_edges);
    finalize_kernel<5, true><<<((n_nodes << 5) + 255) / 256, 256, 0, stream>>>(acc2, g2, dinv, b2, n_nodes);

    // layer 3: 32 -> 1
    gemm3_kernel<<<(n_nodes + 255) / 256, 256, 0, stream>>>(acc2, W3, dinv, g3, n_nodes);
    scatter_kernel<0><<<2048, 256, 0, stream>>>(src, dst, g3, acc3, n_edges);
    finalize3_kernel<<<(n_nodes + 255) / 256, 256, 0, stream>>>(acc3, g3, dinv, b3, out, n_nodes);
}

// Round 2
// 300.228 us; speedup vs baseline: 1.6245x; 1.6245x over previous
//
#include <hip/hip_runtime.h>

// StructuralGcn: 3-layer GCN, N=50000 nodes, E=800000 edges (+ self loops).
// Round 1 -> 2: replace atomic scatter (51M+ f32 atomics, 170us layer-1) with
// dst-sorted CSR + per-node gather aggregation, fusing the finalize epilogue
// (relu(dinv*(acc+g_self)+b)) into the aggregation kernel. Eliminates all f32
// atomics, the 3 accumulator memsets, and the 3 finalize passes.

#define IN_C 128

// ---------------- CSR build: histogram, dinv, scan, fill ----------------

__global__ void hist_kernel(const int* __restrict__ dst, int* __restrict__ cnt,
                            int n_edges) {
    const int stride = gridDim.x * blockDim.x;
    for (int e = blockIdx.x * blockDim.x + threadIdx.x; e < n_edges; e += stride)
        atomicAdd(&cnt[dst[e]], 1);
}

__global__ void dinv_kernel(const int* __restrict__ cnt, float* __restrict__ dinv, int n) {
    const int i = blockIdx.x * blockDim.x + threadIdx.x;
    if (i < n) dinv[i] = rsqrtf((float)cnt[i] + 1.0f);   // +1 = self loop
}

// block sums of cnt (chunk = 256)
__global__ void scan_partial_kernel(const int* __restrict__ cnt, int* __restrict__ partial,
                                    int n) {
    __shared__ int sm[256];
    const int gid = blockIdx.x * 256 + threadIdx.x;
    sm[threadIdx.x] = (gid < n) ? cnt[gid] : 0;
    __syncthreads();
    for (int s = 128; s > 0; s >>= 1) {
        if (threadIdx.x < s) sm[threadIdx.x] += sm[threadIdx.x + s];
        __syncthreads();
    }
    if (threadIdx.x == 0) partial[blockIdx.x] = sm[0];
}

// single-block exclusive scan of block sums (nb <= 256)
__global__ void scan_mid_kernel(int* __restrict__ partial, int nb) {
    __shared__ int sm[256];
    const int t = threadIdx.x;
    sm[t] = (t < nb) ? partial[t] : 0;
    __syncthreads();
    for (int off = 1; off < 256; off <<= 1) {
        const int v = (t >= off) ? sm[t - off] : 0;
        __syncthreads();
        sm[t] += v;
        __syncthreads();
    }
    const int ex = (t == 0) ? 0 : sm[t - 1];
    if (t < nb) partial[t] = ex;
}

// per-block exclusive scan + base -> row_start; also writes row_start[n]
__global__ void scan_final_kernel(const int* __restrict__ cnt, const int* __restrict__ partial,
                                  int* __restrict__ row_start, int n) {
    __shared__ int sm[256];
    const int t = threadIdx.x;
    const int gid = blockIdx.x * 256 + t;
    const int v = (gid < n) ? cnt[gid] : 0;
    sm[t] = v;
    __syncthreads();
    for (int off = 1; off < 256; off <<= 1) {
        const int u = (t >= off) ? sm[t - off] : 0;
        __syncthreads();
        sm[t] += u;
        __syncthreads();
    }
    const int incl = sm[t];
    const int base = partial[blockIdx.x];
    if (gid < n) row_start[gid] = base + incl - v;   // exclusive
    if (gid == n - 1) row_start[n] = base + incl;    // == n_edges
}

__global__ void fill_kernel(const int* __restrict__ src, const int* __restrict__ dst,
                            const int* __restrict__ row_start, int* __restrict__ cursor,
                            int* __restrict__ esrc, int n_edges) {
    const int stride = gridDim.x * blockDim.x;
    for (int e = blockIdx.x * blockDim.x + threadIdx.x; e < n_edges; e += stride) {
        const int d = dst[e];
        const int pos = row_start[d] + atomicAdd(&cursor[d], 1);
        esrc[pos] = src[e];
    }
}

// ---------------- GEMM with dinv-scaled epilogue ----------------
// g[i][c] = (sum_k x[i][k] * W[k][c]) * dinv[i]

template <int KDIM, int COUT>
__global__ __launch_bounds__(256) void gemm_scale_kernel(
    const float* __restrict__ x, const float* __restrict__ W,
    const float* __restrict__ dinv, float* __restrict__ g, int n_nodes) {
    constexpr int NPB = 64;
    constexpr int GROUPS = 256 / COUT;
    constexpr int NPT = NPB / GROUPS;

    const int tid = threadIdx.x;
    const int c = tid % COUT;
    const int grp = tid / COUT;
    const int base = blockIdx.x * NPB;

    float wreg[KDIM];
#pragma unroll
    for (int k = 0; k < KDIM; ++k) wreg[k] = W[k * COUT + c];

    for (int nn = 0; nn < NPT; ++nn) {
        const int node = base + grp + nn * GROUPS;
        if (node >= n_nodes) break;
        const float4* xr = (const float4*)(x + (size_t)node * KDIM);
        float acc = 0.0f;
#pragma unroll
        for (int k4 = 0; k4 < KDIM / 4; ++k4) {
            const float4 xv = xr[k4];
            acc += xv.x * wreg[4 * k4 + 0] + xv.y * wreg[4 * k4 + 1] +
                   xv.z * wreg[4 * k4 + 2] + xv.w * wreg[4 * k4 + 3];
        }
        g[(size_t)node * COUT + c] = acc * dinv[node];
    }
}

__global__ void gemm3_kernel(const float* __restrict__ z2, const float* __restrict__ W3,
                             const float* __restrict__ dinv, float* __restrict__ g3, int n) {
    const int i = blockIdx.x * blockDim.x + threadIdx.x;
    if (i >= n) return;
    const float4* xr = (const float4*)(z2 + (size_t)i * 32);
    float acc = 0.0f;
#pragma unroll
    for (int k4 = 0; k4 < 8; ++k4) {
        const float4 xv = xr[k4];
        acc += xv.x * W3[4 * k4 + 0] + xv.y * W3[4 * k4 + 1] +
               xv.z * W3[4 * k4 + 2] + xv.w * W3[4 * k4 + 3];
    }
    g3[i] = acc * dinv[i];
}

// ---------------- fused CSR aggregation + finalize ----------------

// C=64: one wave per node, lane = channel. z = relu(dinv*(acc + g_self) + b)
__global__ __launch_bounds__(256) void agg_kernel64(
    const int* __restrict__ row_start, const int* __restrict__ esrc,
    const float* __restrict__ g, const float* __restrict__ dinv,
    const float* __restrict__ b, float* __restrict__ z, int n) {
    const int node = blockIdx.x * 4 + (threadIdx.x >> 6);
    if (node >= n) return;
    const int lane = threadIdx.x & 63;
    const int beg = row_start[node], end = row_start[node + 1];
    float acc = 0.0f;
    int e = beg;
    for (; e + 1 < end; e += 2) {               // 2-edge unroll for ILP
        const int s0 = esrc[e], s1 = esrc[e + 1];
        acc += g[(size_t)s0 * 64 + lane];
        acc += g[(size_t)s1 * 64 + lane];
    }
    if (e < end) acc += g[(size_t)esrc[e] * 64 + lane];
    const float v = dinv[node] * (acc + g[(size_t)node * 64 + lane]) + b[lane];
    z[(size_t)node * 64 + lane] = fmaxf(v, 0.0f);
}

// C=32: one wave per node; half-waves process alternating edges, combine via shfl.
__global__ __launch_bounds__(256) void agg_kernel32(
    const int* __restrict__ row_start, const int* __restrict__ esrc,
    const float* __restrict__ g, const float* __restrict__ dinv,
    const float* __restrict__ b, float* __restrict__ z, int n) {
    const int node = blockIdx.x * 4 + (threadIdx.x >> 6);
    if (node >= n) return;
    const int lane = threadIdx.x & 63;
    const int c = lane & 31, h = lane >> 5;
    const int beg = row_start[node], end = row_start[node + 1];
    float acc = 0.0f;
    for (int e = beg + h; e < end; e += 2)
        acc += g[(size_t)esrc[e] * 32 + c];
    acc += __shfl_xor(acc, 32);                 // combine half-wave partials
    if (h == 0) {
        const float v = dinv[node] * (acc + g[(size_t)node * 32 + c]) + b[c];
        z[(size_t)node * 32 + c] = fmaxf(v, 0.0f);
    }
}

// C=1: 8 lanes per node, shfl-reduce. out = dinv*(acc + g_self) + b3 (no relu).
__global__ __launch_bounds__(256) void agg_kernel1(
    const int* __restrict__ row_start, const int* __restrict__ esrc,
    const float* __restrict__ g, const float* __restrict__ dinv,
    const float* __restrict__ b3, float* __restrict__ out, int n) {
    const int node = blockIdx.x * 32 + (threadIdx.x >> 3);
    if (node >= n) return;
    const int l = threadIdx.x & 7;
    const int beg = row_start[node], end = row_start[node + 1];
    float acc = 0.0f;
    for (int e = beg + l; e < end; e += 8)
        acc += g[esrc[e]];
    acc += __shfl_xor(acc, 1);
    acc += __shfl_xor(acc, 2);
    acc += __shfl_xor(acc, 4);
    if (l == 0) out[node] = dinv[node] * (acc + g[node]) + b3[0];
}

// ---------------- launcher ----------------

extern "C" void kernel_launch(void* const* d_in, const int* in_sizes, int n_in,
                              void* d_out, int out_size, void* d_ws, size_t ws_size,
                              hipStream_t stream) {
    const float* x  = (const float*)d_in[0];
    const int*   ei = (const int*)d_in[1];
    const float* W1 = (const float*)d_in[2];
    const float* b1 = (const float*)d_in[3];
    const float* W2 = (const float*)d_in[4];
    const float* b2 = (const float*)d_in[5];
    const float* W3 = (const float*)d_in[6];
    const float* b3 = (const float*)d_in[7];
    float* out = (float*)d_out;

    const int n_nodes = in_sizes[0] / IN_C;    // 50000
    const int n_edges = in_sizes[1] / 2;       // 800000
    const int* src = ei;
    const int* dst = ei + n_edges;
    const int nb = (n_nodes + 255) / 256;      // 196 scan blocks

    auto align_up = [](size_t v) { return (v + 255) & ~(size_t)255; };
    char* p = (char*)d_ws;
    int*   cnt       = (int*)p;   p += align_up((size_t)n_nodes * 4);
    int*   cursor    = (int*)p;   p += align_up((size_t)n_nodes * 4);
    int*   partial   = (int*)p;   p += align_up(256 * 4);
    int*   row_start = (int*)p;   p += align_up(((size_t)n_nodes + 1) * 4);
    int*   esrc      = (int*)p;   p += align_up((size_t)n_edges * 4);
    float* dinv      = (float*)p; p += align_up((size_t)n_nodes * 4);
    float* g1        = (float*)p; p += align_up((size_t)n_nodes * 64 * 4);
    float* z1        = (float*)p; p += align_up((size_t)n_nodes * 64 * 4);
    float* g2        = (float*)p; p += align_up((size_t)n_nodes * 32 * 4);
    float* z2        = (float*)p; p += align_up((size_t)n_nodes * 32 * 4);
    float* g3        = (float*)p; p += align_up((size_t)n_nodes * 4);
    (void)ws_size; (void)n_in; (void)out_size;

    hipMemsetAsync(cnt, 0, (size_t)n_nodes * 4, stream);
    hipMemsetAsync(cursor, 0, (size_t)n_nodes * 4, stream);

    // CSR build + normalization
    hist_kernel<<<2048, 256, 0, stream>>>(dst, cnt, n_edges);
    dinv_kernel<<<nb, 256, 0, stream>>>(cnt, dinv, n_nodes);
    scan_partial_kernel<<<nb, 256, 0, stream>>>(cnt, partial, n_nodes);
    scan_mid_kernel<<<1, 256, 0, stream>>>(partial, nb);
    scan_final_kernel<<<nb, 256, 0, stream>>>(cnt, partial, row_start, n_nodes);
    fill_kernel<<<2048, 256, 0, stream>>>(src, dst, row_start, cursor, esrc, n_edges);

    // layer 1: 128 -> 64, relu
    gemm_scale_kernel<128, 64><<<(n_nodes + 63) / 64, 256, 0, stream>>>(x, W1, dinv, g1, n_nodes);
    agg_kernel64<<<(n_nodes + 3) / 4, 256, 0, stream>>>(row_start, esrc, g1, dinv, b1, z1, n_nodes);

    // layer 2: 64 -> 32, relu
    gemm_scale_kernel<64, 32><<<(n_nodes + 63) / 64, 256, 0, stream>>>(z1, W2, dinv, g2, n_nodes);
    agg_kernel32<<<(n_nodes + 3) / 4, 256, 0, stream>>>(row_start, esrc, g2, dinv, b2, z2, n_nodes);

    // layer 3: 32 -> 1
    gemm3_kernel<<<(n_nodes + 255) / 256, 256, 0, stream>>>(z2, W3, dinv, g3, n_nodes);
    agg_kernel1<<<(n_nodes + 31) / 32, 256, 0, stream>>>(row_start, esrc, g3, dinv, b3, out, n_nodes);
}

// Round 3
// 228.366 us; speedup vs baseline: 2.1357x; 1.3147x over previous
//
#include <hip/hip_runtime.h>

// StructuralGcn: 3-layer GCN, N=50000 nodes, E=800000 edges (+ self loops).
// Round 2 -> 3: the per-thread W-column array (float wreg[128]) was demoted to
// scratch (VGPR_Count=80 < 128 live) -> layer-1 GEMM ran at 95us, latency-bound
// (VALUBusy 14%). Replaced with an LDS-staged, register-blocked GEMM: thread
// owns a 4-node x 4-channel accumulator tile; per 4-k step: 4 broadcast float4
// x loads + 4 ds_read_b128 W loads feed 64 FMAs. No scratch, ~50 live VGPRs.

#define IN_C 128

// ---------------- CSR build: histogram, dinv, scan, fill ----------------

__global__ void hist_kernel(const int* __restrict__ dst, int* __restrict__ cnt,
                            int n_edges) {
    const int stride = gridDim.x * blockDim.x;
    for (int e = blockIdx.x * blockDim.x + threadIdx.x; e < n_edges; e += stride)
        atomicAdd(&cnt[dst[e]], 1);
}

__global__ void dinv_kernel(const int* __restrict__ cnt, float* __restrict__ dinv, int n) {
    const int i = blockIdx.x * blockDim.x + threadIdx.x;
    if (i < n) dinv[i] = rsqrtf((float)cnt[i] + 1.0f);   // +1 = self loop
}

__global__ void scan_partial_kernel(const int* __restrict__ cnt, int* __restrict__ partial,
                                    int n) {
    __shared__ int sm[256];
    const int gid = blockIdx.x * 256 + threadIdx.x;
    sm[threadIdx.x] = (gid < n) ? cnt[gid] : 0;
    __syncthreads();
    for (int s = 128; s > 0; s >>= 1) {
        if (threadIdx.x < s) sm[threadIdx.x] += sm[threadIdx.x + s];
        __syncthreads();
    }
    if (threadIdx.x == 0) partial[blockIdx.x] = sm[0];
}

__global__ void scan_mid_kernel(int* __restrict__ partial, int nb) {
    __shared__ int sm[256];
    const int t = threadIdx.x;
    sm[t] = (t < nb) ? partial[t] : 0;
    __syncthreads();
    for (int off = 1; off < 256; off <<= 1) {
        const int v = (t >= off) ? sm[t - off] : 0;
        __syncthreads();
        sm[t] += v;
        __syncthreads();
    }
    const int ex = (t == 0) ? 0 : sm[t - 1];
    if (t < nb) partial[t] = ex;
}

__global__ void scan_final_kernel(const int* __restrict__ cnt, const int* __restrict__ partial,
                                  int* __restrict__ row_start, int n) {
    __shared__ int sm[256];
    const int t = threadIdx.x;
    const int gid = blockIdx.x * 256 + t;
    const int v = (gid < n) ? cnt[gid] : 0;
    sm[t] = v;
    __syncthreads();
    for (int off = 1; off < 256; off <<= 1) {
        const int u = (t >= off) ? sm[t - off] : 0;
        __syncthreads();
        sm[t] += u;
        __syncthreads();
    }
    const int incl = sm[t];
    const int base = partial[blockIdx.x];
    if (gid < n) row_start[gid] = base + incl - v;
    if (gid == n - 1) row_start[n] = base + incl;
}

__global__ void fill_kernel(const int* __restrict__ src, const int* __restrict__ dst,
                            const int* __restrict__ row_start, int* __restrict__ cursor,
                            int* __restrict__ esrc, int n_edges) {
    const int stride = gridDim.x * blockDim.x;
    for (int e = blockIdx.x * blockDim.x + threadIdx.x; e < n_edges; e += stride) {
        const int d = dst[e];
        const int pos = row_start[d] + atomicAdd(&cursor[d], 1);
        esrc[pos] = src[e];
    }
}

// ---------------- register-blocked GEMM with dinv epilogue ----------------
// g[i][c] = (sum_k x[i][k] * W[k][c]) * dinv[i]
// Block = 256 threads. Thread = 4 nodes x 4 channels. W staged in LDS.

template <int KDIM, int COUT>
__global__ __launch_bounds__(256) void gemm_tile_kernel(
    const float* __restrict__ x, const float* __restrict__ W,
    const float* __restrict__ dinv, float* __restrict__ g, int n_nodes) {
    constexpr int CT = COUT / 4;        // channel groups: 16 (C=64) / 8 (C=32)
    constexpr int NG = 256 / CT;        // node groups:    16 / 32
    constexpr int NT = NG * 4;          // nodes per block: 64 / 128

    __shared__ float Wl[KDIM * COUT];
    const int tid = threadIdx.x;
#pragma unroll
    for (int i = 0; i < KDIM * COUT / 1024; ++i) {
        const int idx = (i * 256 + tid) * 4;
        *(float4*)&Wl[idx] = *(const float4*)&W[idx];
    }
    __syncthreads();

    const int tx = tid % CT;
    const int ty = tid / CT;
    const int c0 = tx * 4;
    const int n0 = blockIdx.x * NT + ty * 4;

    const float4* xr[4];
#pragma unroll
    for (int nn = 0; nn < 4; ++nn) {
        const int node = n0 + nn;
        xr[nn] = (const float4*)(x + (size_t)(node < n_nodes ? node : 0) * KDIM);
    }

    float acc[4][4] = {};
#pragma unroll 4
    for (int k4 = 0; k4 < KDIM / 4; ++k4) {
        float4 xv[4], wv[4];
#pragma unroll
        for (int nn = 0; nn < 4; ++nn) xv[nn] = xr[nn][k4];
#pragma unroll
        for (int kk = 0; kk < 4; ++kk)
            wv[kk] = *(const float4*)&Wl[(k4 * 4 + kk) * COUT + c0];
#pragma unroll
        for (int nn = 0; nn < 4; ++nn) {
            const float xs0 = xv[nn].x, xs1 = xv[nn].y, xs2 = xv[nn].z, xs3 = xv[nn].w;
            acc[nn][0] = fmaf(xs0, wv[0].x, fmaf(xs1, wv[1].x, fmaf(xs2, wv[2].x, fmaf(xs3, wv[3].x, acc[nn][0]))));
            acc[nn][1] = fmaf(xs0, wv[0].y, fmaf(xs1, wv[1].y, fmaf(xs2, wv[2].y, fmaf(xs3, wv[3].y, acc[nn][1]))));
            acc[nn][2] = fmaf(xs0, wv[0].z, fmaf(xs1, wv[1].z, fmaf(xs2, wv[2].z, fmaf(xs3, wv[3].z, acc[nn][2]))));
            acc[nn][3] = fmaf(xs0, wv[0].w, fmaf(xs1, wv[1].w, fmaf(xs2, wv[2].w, fmaf(xs3, wv[3].w, acc[nn][3]))));
        }
    }

#pragma unroll
    for (int nn = 0; nn < 4; ++nn) {
        const int node = n0 + nn;
        if (node < n_nodes) {
            const float dv = dinv[node];
            float4 o;
            o.x = acc[nn][0] * dv; o.y = acc[nn][1] * dv;
            o.z = acc[nn][2] * dv; o.w = acc[nn][3] * dv;
            *(float4*)&g[(size_t)node * COUT + c0] = o;
        }
    }
}

__global__ void gemm3_kernel(const float* __restrict__ z2, const float* __restrict__ W3,
                             const float* __restrict__ dinv, float* __restrict__ g3, int n) {
    const int i = blockIdx.x * blockDim.x + threadIdx.x;
    if (i >= n) return;
    const float4* xr = (const float4*)(z2 + (size_t)i * 32);
    float acc = 0.0f;
#pragma unroll
    for (int k4 = 0; k4 < 8; ++k4) {
        const float4 xv = xr[k4];
        acc += xv.x * W3[4 * k4 + 0] + xv.y * W3[4 * k4 + 1] +
               xv.z * W3[4 * k4 + 2] + xv.w * W3[4 * k4 + 3];
    }
    g3[i] = acc * dinv[i];
}

// ---------------- fused CSR aggregation + finalize ----------------

__global__ __launch_bounds__(256) void agg_kernel64(
    const int* __restrict__ row_start, const int* __restrict__ esrc,
    const float* __restrict__ g, const float* __restrict__ dinv,
    const float* __restrict__ b, float* __restrict__ z, int n) {
    const int node = blockIdx.x * 4 + (threadIdx.x >> 6);
    if (node >= n) return;
    const int lane = threadIdx.x & 63;
    const int beg = row_start[node], end = row_start[node + 1];
    float acc = 0.0f;
    int e = beg;
    for (; e + 1 < end; e += 2) {
        const int s0 = esrc[e], s1 = esrc[e + 1];
        acc += g[(size_t)s0 * 64 + lane];
        acc += g[(size_t)s1 * 64 + lane];
    }
    if (e < end) acc += g[(size_t)esrc[e] * 64 + lane];
    const float v = dinv[node] * (acc + g[(size_t)node * 64 + lane]) + b[lane];
    z[(size_t)node * 64 + lane] = fmaxf(v, 0.0f);
}

__global__ __launch_bounds__(256) void agg_kernel32(
    const int* __restrict__ row_start, const int* __restrict__ esrc,
    const float* __restrict__ g, const float* __restrict__ dinv,
    const float* __restrict__ b, float* __restrict__ z, int n) {
    const int node = blockIdx.x * 4 + (threadIdx.x >> 6);
    if (node >= n) return;
    const int lane = threadIdx.x & 63;
    const int c = lane & 31, h = lane >> 5;
    const int beg = row_start[node], end = row_start[node + 1];
    float acc = 0.0f;
    for (int e = beg + h; e < end; e += 2)
        acc += g[(size_t)esrc[e] * 32 + c];
    acc += __shfl_xor(acc, 32);
    if (h == 0) {
        const float v = dinv[node] * (acc + g[(size_t)node * 32 + c]) + b[c];
        z[(size_t)node * 32 + c] = fmaxf(v, 0.0f);
    }
}

__global__ __launch_bounds__(256) void agg_kernel1(
    const int* __restrict__ row_start, const int* __restrict__ esrc,
    const float* __restrict__ g, const float* __restrict__ dinv,
    const float* __restrict__ b3, float* __restrict__ out, int n) {
    const int node = blockIdx.x * 32 + (threadIdx.x >> 3);
    if (node >= n) return;
    const int l = threadIdx.x & 7;
    const int beg = row_start[node], end = row_start[node + 1];
    float acc = 0.0f;
    for (int e = beg + l; e < end; e += 8)
        acc += g[esrc[e]];
    acc += __shfl_xor(acc, 1);
    acc += __shfl_xor(acc, 2);
    acc += __shfl_xor(acc, 4);
    if (l == 0) out[node] = dinv[node] * (acc + g[node]) + b3[0];
}

// ---------------- launcher ----------------

extern "C" void kernel_launch(void* const* d_in, const int* in_sizes, int n_in,
                              void* d_out, int out_size, void* d_ws, size_t ws_size,
                              hipStream_t stream) {
    const float* x  = (const float*)d_in[0];
    const int*   ei = (const int*)d_in[1];
    const float* W1 = (const float*)d_in[2];
    const float* b1 = (const float*)d_in[3];
    const float* W2 = (const float*)d_in[4];
    const float* b2 = (const float*)d_in[5];
    const float* W3 = (const float*)d_in[6];
    const float* b3 = (const float*)d_in[7];
    float* out = (float*)d_out;

    const int n_nodes = in_sizes[0] / IN_C;    // 50000
    const int n_edges = in_sizes[1] / 2;       // 800000
    const int* src = ei;
    const int* dst = ei + n_edges;
    const int nb = (n_nodes + 255) / 256;

    auto align_up = [](size_t v) { return (v + 255) & ~(size_t)255; };
    char* p = (char*)d_ws;
    int*   cnt       = (int*)p;   p += align_up((size_t)n_nodes * 4);
    int*   cursor    = (int*)p;   p += align_up((size_t)n_nodes * 4);
    int*   partial   = (int*)p;   p += align_up(256 * 4);
    int*   row_start = (int*)p;   p += align_up(((size_t)n_nodes + 1) * 4);
    int*   esrc      = (int*)p;   p += align_up((size_t)n_edges * 4);
    float* dinv      = (float*)p; p += align_up((size_t)n_nodes * 4);
    float* g1        = (float*)p; p += align_up((size_t)n_nodes * 64 * 4);
    float* z1        = (float*)p; p += align_up((size_t)n_nodes * 64 * 4);
    float* g2        = (float*)p; p += align_up((size_t)n_nodes * 32 * 4);
    float* z2        = (float*)p; p += align_up((size_t)n_nodes * 32 * 4);
    float* g3        = (float*)p; p += align_up((size_t)n_nodes * 4);
    (void)ws_size; (void)n_in; (void)out_size;

    hipMemsetAsync(cnt, 0, (size_t)n_nodes * 4, stream);
    hipMemsetAsync(cursor, 0, (size_t)n_nodes * 4, stream);

    hist_kernel<<<2048, 256, 0, stream>>>(dst, cnt, n_edges);
    dinv_kernel<<<nb, 256, 0, stream>>>(cnt, dinv, n_nodes);
    scan_partial_kernel<<<nb, 256, 0, stream>>>(cnt, partial, n_nodes);
    scan_mid_kernel<<<1, 256, 0, stream>>>(partial, nb);
    scan_final_kernel<<<nb, 256, 0, stream>>>(cnt, partial, row_start, n_nodes);
    fill_kernel<<<2048, 256, 0, stream>>>(src, dst, row_start, cursor, esrc, n_edges);

    // layer 1: 128 -> 64, relu
    gemm_tile_kernel<128, 64><<<(n_nodes + 63) / 64, 256, 0, stream>>>(x, W1, dinv, g1, n_nodes);
    agg_kernel64<<<(n_nodes + 3) / 4, 256, 0, stream>>>(row_start, esrc, g1, dinv, b1, z1, n_nodes);

    // layer 2: 64 -> 32, relu
    gemm_tile_kernel<64, 32><<<(n_nodes + 127) / 128, 256, 0, stream>>>(z1, W2, dinv, g2, n_nodes);
    agg_kernel32<<<(n_nodes + 3) / 4, 256, 0, stream>>>(row_start, esrc, g2, dinv, b2, z2, n_nodes);

    // layer 3: 32 -> 1
    gemm3_kernel<<<(n_nodes + 255) / 256, 256, 0, stream>>>(z2, W3, dinv, g3, n_nodes);
    agg_kernel1<<<(n_nodes + 31) / 32, 256, 0, stream>>>(row_start, esrc, g3, dinv, b3, out, n_nodes);
}

// Round 4
// 195.412 us; speedup vs baseline: 2.4959x; 1.1686x over previous
//
#include <hip/hip_runtime.h>

// StructuralGcn: 3-layer GCN, N=50000 nodes, E=800000 edges (+ self loops).
// Round 3 -> 4: agg kernels were latency/MLP-bound (51us, 2x 256B gathers in
// flight per wave). Now each lane gathers a float4 and a wave processes 4
// (C=64) / 8 (C=32) edges per load instruction, unrolled x2 -> 2KB in flight
// per wave; edge-slot partials combined via __shfl_xor. Also: dinv folded into
// scan_final; fill cursor seeded by d2d copy of row_start.

#define IN_C 128

// ---------------- CSR build: histogram, scan(+dinv), fill ----------------

__global__ void hist_kernel(const int* __restrict__ dst, int* __restrict__ cnt,
                            int n_edges) {
    const int stride = gridDim.x * blockDim.x;
    for (int e = blockIdx.x * blockDim.x + threadIdx.x; e < n_edges; e += stride)
        atomicAdd(&cnt[dst[e]], 1);
}

__global__ void scan_partial_kernel(const int* __restrict__ cnt, int* __restrict__ partial,
                                    int n) {
    __shared__ int sm[256];
    const int gid = blockIdx.x * 256 + threadIdx.x;
    sm[threadIdx.x] = (gid < n) ? cnt[gid] : 0;
    __syncthreads();
    for (int s = 128; s > 0; s >>= 1) {
        if (threadIdx.x < s) sm[threadIdx.x] += sm[threadIdx.x + s];
        __syncthreads();
    }
    if (threadIdx.x == 0) partial[blockIdx.x] = sm[0];
}

__global__ void scan_mid_kernel(int* __restrict__ partial, int nb) {
    __shared__ int sm[256];
    const int t = threadIdx.x;
    sm[t] = (t < nb) ? partial[t] : 0;
    __syncthreads();
    for (int off = 1; off < 256; off <<= 1) {
        const int v = (t >= off) ? sm[t - off] : 0;
        __syncthreads();
        sm[t] += v;
        __syncthreads();
    }
    const int ex = (t == 0) ? 0 : sm[t - 1];
    if (t < nb) partial[t] = ex;
}

// exclusive scan -> row_start, plus dinv = rsqrt(deg+1) fused in
__global__ void scan_final_kernel(const int* __restrict__ cnt, const int* __restrict__ partial,
                                  int* __restrict__ row_start, float* __restrict__ dinv,
                                  int n) {
    __shared__ int sm[256];
    const int t = threadIdx.x;
    const int gid = blockIdx.x * 256 + t;
    const int v = (gid < n) ? cnt[gid] : 0;
    sm[t] = v;
    __syncthreads();
    for (int off = 1; off < 256; off <<= 1) {
        const int u = (t >= off) ? sm[t - off] : 0;
        __syncthreads();
        sm[t] += u;
        __syncthreads();
    }
    const int incl = sm[t];
    const int base = partial[blockIdx.x];
    if (gid < n) {
        row_start[gid] = base + incl - v;
        dinv[gid] = rsqrtf((float)v + 1.0f);   // +1 = self loop
    }
    if (gid == n - 1) row_start[n] = base + incl;
}

// cursor pre-seeded with row_start (d2d copy) -> atomic returns global slot
__global__ void fill_kernel(const int* __restrict__ src, const int* __restrict__ dst,
                            int* __restrict__ cursor, int* __restrict__ esrc, int n_edges) {
    const int stride = gridDim.x * blockDim.x;
    for (int e = blockIdx.x * blockDim.x + threadIdx.x; e < n_edges; e += stride) {
        const int pos = atomicAdd(&cursor[dst[e]], 1);
        esrc[pos] = src[e];
    }
}

// ---------------- register-blocked GEMM with dinv epilogue ----------------

template <int KDIM, int COUT>
__global__ __launch_bounds__(256) void gemm_tile_kernel(
    const float* __restrict__ x, const float* __restrict__ W,
    const float* __restrict__ dinv, float* __restrict__ g, int n_nodes) {
    constexpr int CT = COUT / 4;
    constexpr int NG = 256 / CT;
    constexpr int NT = NG * 4;

    __shared__ float Wl[KDIM * COUT];
    const int tid = threadIdx.x;
#pragma unroll
    for (int i = 0; i < KDIM * COUT / 1024; ++i) {
        const int idx = (i * 256 + tid) * 4;
        *(float4*)&Wl[idx] = *(const float4*)&W[idx];
    }
    __syncthreads();

    const int tx = tid % CT;
    const int ty = tid / CT;
    const int c0 = tx * 4;
    const int n0 = blockIdx.x * NT + ty * 4;

    const float4* xr[4];
#pragma unroll
    for (int nn = 0; nn < 4; ++nn) {
        const int node = n0 + nn;
        xr[nn] = (const float4*)(x + (size_t)(node < n_nodes ? node : 0) * KDIM);
    }

    float acc[4][4] = {};
#pragma unroll 4
    for (int k4 = 0; k4 < KDIM / 4; ++k4) {
        float4 xv[4], wv[4];
#pragma unroll
        for (int nn = 0; nn < 4; ++nn) xv[nn] = xr[nn][k4];
#pragma unroll
        for (int kk = 0; kk < 4; ++kk)
            wv[kk] = *(const float4*)&Wl[(k4 * 4 + kk) * COUT + c0];
#pragma unroll
        for (int nn = 0; nn < 4; ++nn) {
            const float xs0 = xv[nn].x, xs1 = xv[nn].y, xs2 = xv[nn].z, xs3 = xv[nn].w;
            acc[nn][0] = fmaf(xs0, wv[0].x, fmaf(xs1, wv[1].x, fmaf(xs2, wv[2].x, fmaf(xs3, wv[3].x, acc[nn][0]))));
            acc[nn][1] = fmaf(xs0, wv[0].y, fmaf(xs1, wv[1].y, fmaf(xs2, wv[2].y, fmaf(xs3, wv[3].y, acc[nn][1]))));
            acc[nn][2] = fmaf(xs0, wv[0].z, fmaf(xs1, wv[1].z, fmaf(xs2, wv[2].z, fmaf(xs3, wv[3].z, acc[nn][2]))));
            acc[nn][3] = fmaf(xs0, wv[0].w, fmaf(xs1, wv[1].w, fmaf(xs2, wv[2].w, fmaf(xs3, wv[3].w, acc[nn][3]))));
        }
    }

#pragma unroll
    for (int nn = 0; nn < 4; ++nn) {
        const int node = n0 + nn;
        if (node < n_nodes) {
            const float dv = dinv[node];
            float4 o;
            o.x = acc[nn][0] * dv; o.y = acc[nn][1] * dv;
            o.z = acc[nn][2] * dv; o.w = acc[nn][3] * dv;
            *(float4*)&g[(size_t)node * COUT + c0] = o;
        }
    }
}

__global__ void gemm3_kernel(const float* __restrict__ z2, const float* __restrict__ W3,
                             const float* __restrict__ dinv, float* __restrict__ g3, int n) {
    const int i = blockIdx.x * blockDim.x + threadIdx.x;
    if (i >= n) return;
    const float4* xr = (const float4*)(z2 + (size_t)i * 32);
    float acc = 0.0f;
#pragma unroll
    for (int k4 = 0; k4 < 8; ++k4) {
        const float4 xv = xr[k4];
        acc += xv.x * W3[4 * k4 + 0] + xv.y * W3[4 * k4 + 1] +
               xv.z * W3[4 * k4 + 2] + xv.w * W3[4 * k4 + 3];
    }
    g3[i] = acc * dinv[i];
}

// ---------------- fused CSR aggregation + finalize ----------------
// C=64: wave per node; lane = (edge_slot es=lane>>4) x (channel-quad cg=lane&15).
// 4 edges per float4-load instruction, unrolled x2 (8 edges / 2KB in flight).

__global__ __launch_bounds__(256) void agg_kernel64(
    const int* __restrict__ row_start, const int* __restrict__ esrc,
    const float* __restrict__ g, const float* __restrict__ dinv,
    const float* __restrict__ b, float* __restrict__ z, int n) {
    const int node = blockIdx.x * 4 + (threadIdx.x >> 6);
    if (node >= n) return;
    const int lane = threadIdx.x & 63;
    const int cg = lane & 15;
    const int es = lane >> 4;
    const float4* __restrict__ g4 = (const float4*)g;
    const int beg = row_start[node], end = row_start[node + 1];
    float4 a0 = {0, 0, 0, 0}, a1 = {0, 0, 0, 0};
    int e = beg;
    for (; e + 8 <= end; e += 8) {
        const int s0 = esrc[e + es];
        const int s1 = esrc[e + 4 + es];
        const float4 v0 = g4[(size_t)s0 * 16 + cg];
        const float4 v1 = g4[(size_t)s1 * 16 + cg];
        a0.x += v0.x; a0.y += v0.y; a0.z += v0.z; a0.w += v0.w;
        a1.x += v1.x; a1.y += v1.y; a1.z += v1.z; a1.w += v1.w;
    }
    for (; e < end; e += 4) {
        if (e + es < end) {
            const int s = esrc[e + es];
            const float4 v = g4[(size_t)s * 16 + cg];
            a0.x += v.x; a0.y += v.y; a0.z += v.z; a0.w += v.w;
        }
    }
    a0.x += a1.x; a0.y += a1.y; a0.z += a1.z; a0.w += a1.w;
    a0.x += __shfl_xor(a0.x, 16); a0.y += __shfl_xor(a0.y, 16);
    a0.z += __shfl_xor(a0.z, 16); a0.w += __shfl_xor(a0.w, 16);
    a0.x += __shfl_xor(a0.x, 32); a0.y += __shfl_xor(a0.y, 32);
    a0.z += __shfl_xor(a0.z, 32); a0.w += __shfl_xor(a0.w, 32);
    if (es == 0) {
        const float dv = dinv[node];
        const float4 gs = g4[(size_t)node * 16 + cg];
        const float4 bb = *(const float4*)&b[cg * 4];
        float4 o;
        o.x = fmaxf(dv * (a0.x + gs.x) + bb.x, 0.0f);
        o.y = fmaxf(dv * (a0.y + gs.y) + bb.y, 0.0f);
        o.z = fmaxf(dv * (a0.z + gs.z) + bb.z, 0.0f);
        o.w = fmaxf(dv * (a0.w + gs.w) + bb.w, 0.0f);
        ((float4*)z)[(size_t)node * 16 + cg] = o;
    }
}

// C=32: wave per node; 8 edge slots x 8 channel-quads; 8 edges per instruction.
__global__ __launch_bounds__(256) void agg_kernel32(
    const int* __restrict__ row_start, const int* __restrict__ esrc,
    const float* __restrict__ g, const float* __restrict__ dinv,
    const float* __restrict__ b, float* __restrict__ z, int n) {
    const int node = blockIdx.x * 4 + (threadIdx.x >> 6);
    if (node >= n) return;
    const int lane = threadIdx.x & 63;
    const int cg = lane & 7;
    const int es = lane >> 3;
    const float4* __restrict__ g4 = (const float4*)g;
    const int beg = row_start[node], end = row_start[node + 1];
    float4 a0 = {0, 0, 0, 0}, a1 = {0, 0, 0, 0};
    int e = beg;
    for (; e + 16 <= end; e += 16) {
        const int s0 = esrc[e + es];
        const int s1 = esrc[e + 8 + es];
        const float4 v0 = g4[(size_t)s0 * 8 + cg];
        const float4 v1 = g4[(size_t)s1 * 8 + cg];
        a0.x += v0.x; a0.y += v0.y; a0.z += v0.z; a0.w += v0.w;
        a1.x += v1.x; a1.y += v1.y; a1.z += v1.z; a1.w += v1.w;
    }
    for (; e < end; e += 8) {
        if (e + es < end) {
            const int s = esrc[e + es];
            const float4 v = g4[(size_t)s * 8 + cg];
            a0.x += v.x; a0.y += v.y; a0.z += v.z; a0.w += v.w;
        }
    }
    a0.x += a1.x; a0.y += a1.y; a0.z += a1.z; a0.w += a1.w;
#pragma unroll
    for (int m = 8; m < 64; m <<= 1) {
        a0.x += __shfl_xor(a0.x, m); a0.y += __shfl_xor(a0.y, m);
        a0.z += __shfl_xor(a0.z, m); a0.w += __shfl_xor(a0.w, m);
    }
    if (es == 0) {
        const float dv = dinv[node];
        const float4 gs = g4[(size_t)node * 8 + cg];
        const float4 bb = *(const float4*)&b[cg * 4];
        float4 o;
        o.x = fmaxf(dv * (a0.x + gs.x) + bb.x, 0.0f);
        o.y = fmaxf(dv * (a0.y + gs.y) + bb.y, 0.0f);
        o.z = fmaxf(dv * (a0.z + gs.z) + bb.z, 0.0f);
        o.w = fmaxf(dv * (a0.w + gs.w) + bb.w, 0.0f);
        ((float4*)z)[(size_t)node * 8 + cg] = o;
    }
}

__global__ __launch_bounds__(256) void agg_kernel1(
    const int* __restrict__ row_start, const int* __restrict__ esrc,
    const float* __restrict__ g, const float* __restrict__ dinv,
    const float* __restrict__ b3, float* __restrict__ out, int n) {
    const int node = blockIdx.x * 32 + (threadIdx.x >> 3);
    if (node >= n) return;
    const int l = threadIdx.x & 7;
    const int beg = row_start[node], end = row_start[node + 1];
    float acc = 0.0f;
    for (int e = beg + l; e < end; e += 8)
        acc += g[esrc[e]];
    acc += __shfl_xor(acc, 1);
    acc += __shfl_xor(acc, 2);
    acc += __shfl_xor(acc, 4);
    if (l == 0) out[node] = dinv[node] * (acc + g[node]) + b3[0];
}

// ---------------- launcher ----------------

extern "C" void kernel_launch(void* const* d_in, const int* in_sizes, int n_in,
                              void* d_out, int out_size, void* d_ws, size_t ws_size,
                              hipStream_t stream) {
    const float* x  = (const float*)d_in[0];
    const int*   ei = (const int*)d_in[1];
    const float* W1 = (const float*)d_in[2];
    const float* b1 = (const float*)d_in[3];
    const float* W2 = (const float*)d_in[4];
    const float* b2 = (const float*)d_in[5];
    const float* W3 = (const float*)d_in[6];
    const float* b3 = (const float*)d_in[7];
    float* out = (float*)d_out;

    const int n_nodes = in_sizes[0] / IN_C;    // 50000
    const int n_edges = in_sizes[1] / 2;       // 800000
    const int* src = ei;
    const int* dst = ei + n_edges;
    const int nb = (n_nodes + 255) / 256;

    auto align_up = [](size_t v) { return (v + 255) & ~(size_t)255; };
    char* p = (char*)d_ws;
    int*   cnt       = (int*)p;   p += align_up((size_t)n_nodes * 4);
    int*   cursor    = (int*)p;   p += align_up((size_t)n_nodes * 4);
    int*   partial   = (int*)p;   p += align_up(256 * 4);
    int*   row_start = (int*)p;   p += align_up(((size_t)n_nodes + 1) * 4);
    int*   esrc      = (int*)p;   p += align_up((size_t)n_edges * 4);
    float* dinv      = (float*)p; p += align_up((size_t)n_nodes * 4);
    float* g1        = (float*)p; p += align_up((size_t)n_nodes * 64 * 4);
    float* z1        = (float*)p; p += align_up((size_t)n_nodes * 64 * 4);
    float* g2        = (float*)p; p += align_up((size_t)n_nodes * 32 * 4);
    float* z2        = (float*)p; p += align_up((size_t)n_nodes * 32 * 4);
    float* g3        = (float*)p; p += align_up((size_t)n_nodes * 4);
    (void)ws_size; (void)n_in; (void)out_size;

    hipMemsetAsync(cnt, 0, (size_t)n_nodes * 4, stream);

    // CSR build + normalization
    hist_kernel<<<2048, 256, 0, stream>>>(dst, cnt, n_edges);
    scan_partial_kernel<<<nb, 256, 0, stream>>>(cnt, partial, n_nodes);
    scan_mid_kernel<<<1, 256, 0, stream>>>(partial, nb);
    scan_final_kernel<<<nb, 256, 0, stream>>>(cnt, partial, row_start, dinv, n_nodes);
    hipMemcpyAsync(cursor, row_start, (size_t)n_nodes * 4, hipMemcpyDeviceToDevice, stream);
    fill_kernel<<<2048, 256, 0, stream>>>(src, dst, cursor, esrc, n_edges);

    // layer 1: 128 -> 64, relu
    gemm_tile_kernel<128, 64><<<(n_nodes + 63) / 64, 256, 0, stream>>>(x, W1, dinv, g1, n_nodes);
    agg_kernel64<<<(n_nodes + 3) / 4, 256, 0, stream>>>(row_start, esrc, g1, dinv, b1, z1, n_nodes);

    // layer 2: 64 -> 32, relu
    gemm_tile_kernel<64, 32><<<(n_nodes + 127) / 128, 256, 0, stream>>>(z1, W2, dinv, g2, n_nodes);
    agg_kernel32<<<(n_nodes + 3) / 4, 256, 0, stream>>>(row_start, esrc, g2, dinv, b2, z2, n_nodes);

    // layer 3: 32 -> 1
    gemm3_kernel<<<(n_nodes + 255) / 256, 256, 0, stream>>>(z2, W3, dinv, g3, n_nodes);
    agg_kernel1<<<(n_nodes + 31) / 32, 256, 0, stream>>>(row_start, esrc, g3, dinv, b3, out, n_nodes);
}

// Round 5
// 165.914 us; speedup vs baseline: 2.9396x; 1.1778x over previous
//
#include <hip/hip_runtime.h>

// StructuralGcn: 3-layer GCN, N=50000 nodes, E=800000 edges (+ self loops).
// Round 4 -> 5: fill_kernel wrote 51.7MB HBM for a 3.2MB esrc array (every
// scattered 4B store = its own 64B line writeback; sibling stores on a line
// came from different XCDs -> no merging; VALUBusy 0.4%). Replaced with a
// locality-aware two-pass fill:
//   partition_kernel: block-local LDS counting sort by bucket (dst>>8, 256
//     nodes/bucket), then coalesced run-writes of (dst,src) pairs.
//   local_fill_kernel: one block per bucket, LDS per-node cursors, stores
//     esrc inside the bucket's contiguous ~16KB window (single-CU -> merged).
// Bucket bases are row_start[b<<8], seeded for free in scan_final.

#define IN_C 128
#define NPB_SHIFT 8   // 256 nodes per bucket

// ---------------- CSR build: histogram, scan(+dinv+bucketcur) ----------------

__global__ void hist_kernel(const int* __restrict__ dst, int* __restrict__ cnt,
                            int n_edges) {
    const int stride = gridDim.x * blockDim.x;
    for (int e = blockIdx.x * blockDim.x + threadIdx.x; e < n_edges; e += stride)
        atomicAdd(&cnt[dst[e]], 1);
}

__global__ void scan_partial_kernel(const int* __restrict__ cnt, int* __restrict__ partial,
                                    int n) {
    __shared__ int sm[256];
    const int gid = blockIdx.x * 256 + threadIdx.x;
    sm[threadIdx.x] = (gid < n) ? cnt[gid] : 0;
    __syncthreads();
    for (int s = 128; s > 0; s >>= 1) {
        if (threadIdx.x < s) sm[threadIdx.x] += sm[threadIdx.x + s];
        __syncthreads();
    }
    if (threadIdx.x == 0) partial[blockIdx.x] = sm[0];
}

__global__ void scan_mid_kernel(int* __restrict__ partial, int nb) {
    __shared__ int sm[256];
    const int t = threadIdx.x;
    sm[t] = (t < nb) ? partial[t] : 0;
    __syncthreads();
    for (int off = 1; off < 256; off <<= 1) {
        const int v = (t >= off) ? sm[t - off] : 0;
        __syncthreads();
        sm[t] += v;
        __syncthreads();
    }
    const int ex = (t == 0) ? 0 : sm[t - 1];
    if (t < nb) partial[t] = ex;
}

// exclusive scan -> row_start, dinv = rsqrt(deg+1), bucket bases seeded
__global__ void scan_final_kernel(const int* __restrict__ cnt, const int* __restrict__ partial,
                                  int* __restrict__ row_start, float* __restrict__ dinv,
                                  int* __restrict__ bucketcur, int n) {
    __shared__ int sm[256];
    const int t = threadIdx.x;
    const int gid = blockIdx.x * 256 + t;
    const int v = (gid < n) ? cnt[gid] : 0;
    sm[t] = v;
    __syncthreads();
    for (int off = 1; off < 256; off <<= 1) {
        const int u = (t >= off) ? sm[t - off] : 0;
        __syncthreads();
        sm[t] += u;
        __syncthreads();
    }
    const int incl = sm[t];
    const int base = partial[blockIdx.x];
    if (gid < n) {
        const int rs = base + incl - v;
        row_start[gid] = rs;
        dinv[gid] = rsqrtf((float)v + 1.0f);   // +1 = self loop
        if ((gid & ((1 << NPB_SHIFT) - 1)) == 0) bucketcur[gid >> NPB_SHIFT] = rs;
    }
    if (gid == n - 1) row_start[n] = base + incl;
}

// ---------------- two-pass locality-aware fill ----------------
// Pass 1: block-local counting sort of 2048 edges by bucket, then coalesced
// run-writes of (dst,src) into per-bucket regions reserved via one global
// atomic per (block, bucket).

__global__ __launch_bounds__(256) void partition_kernel(
    const int* __restrict__ src, const int* __restrict__ dst,
    int* __restrict__ bucketcur, int2* __restrict__ tmp, int n_edges, int nb) {
    constexpr int EPT = 8;                 // edges per thread
    __shared__ int hist[256];
    __shared__ int excl[256];
    __shared__ int rankc[256];
    __shared__ int gbase[256];
    __shared__ int2 sorted[256 * EPT];     // 16 KB

    const int t = threadIdx.x;
    const int e0 = blockIdx.x * 256 * EPT;
    hist[t] = 0;
    rankc[t] = 0;
    __syncthreads();

    int d[EPT], s[EPT];
#pragma unroll
    for (int i = 0; i < EPT; ++i) {
        const int e = e0 + t + i * 256;    // coalesced
        if (e < n_edges) {
            d[i] = dst[e];
            s[i] = src[e];
            atomicAdd(&hist[d[i] >> NPB_SHIFT], 1);
        } else {
            d[i] = -1;
        }
    }
    __syncthreads();

    // inclusive Hillis-Steele scan of hist -> excl, then convert to exclusive
    const int hv = hist[t];
    excl[t] = hv;
    __syncthreads();
    for (int off = 1; off < 256; off <<= 1) {
        const int u = (t >= off) ? excl[t - off] : 0;
        __syncthreads();
        excl[t] += u;
        __syncthreads();
    }
    const int ex = excl[t] - hv;
    __syncthreads();
    excl[t] = ex;
    if (t < nb && hv > 0) gbase[t] = atomicAdd(&bucketcur[t], hv);
    __syncthreads();

    // scatter into LDS in bucket-sorted order
#pragma unroll
    for (int i = 0; i < EPT; ++i) {
        if (d[i] >= 0) {
            const int b = d[i] >> NPB_SHIFT;
            const int r = atomicAdd(&rankc[b], 1);
            sorted[excl[b] + r] = make_int2(d[i], s[i]);
        }
    }
    __syncthreads();

    // coalesced run-writes to global bucket regions
    const int m = min(256 * EPT, n_edges - e0);
    for (int i = t; i < m; i += 256) {
        const int2 p = sorted[i];
        const int b = p.x >> NPB_SHIFT;
        tmp[gbase[b] + (i - excl[b])] = p;
    }
}

// Pass 2: one block per bucket; LDS per-node cursors; stores land inside the
// bucket's contiguous esrc window.
__global__ __launch_bounds__(256) void local_fill_kernel(
    const int2* __restrict__ tmp, const int* __restrict__ row_start,
    int* __restrict__ esrc, int n_nodes, int n_edges) {
    __shared__ int cur[1 << NPB_SHIFT];
    const int b = blockIdx.x;
    const int n0 = b << NPB_SHIFT;
    const int t = threadIdx.x;
    const int node = n0 + t;
    cur[t] = (node < n_nodes) ? row_start[node] : 0;
    const int beg = row_start[n0];
    const int endnode = min(n0 + (1 << NPB_SHIFT), n_nodes);
    const int end = row_start[endnode];
    __syncthreads();
    for (int i = beg + t; i < end; i += 256) {
        const int2 p = tmp[i];
        const int pos = atomicAdd(&cur[p.x & ((1 << NPB_SHIFT) - 1)], 1);
        esrc[pos] = p.y;
    }
}

// ---------------- register-blocked GEMM with dinv epilogue ----------------

template <int KDIM, int COUT>
__global__ __launch_bounds__(256) void gemm_tile_kernel(
    const float* __restrict__ x, const float* __restrict__ W,
    const float* __restrict__ dinv, float* __restrict__ g, int n_nodes) {
    constexpr int CT = COUT / 4;
    constexpr int NG = 256 / CT;
    constexpr int NT = NG * 4;

    __shared__ float Wl[KDIM * COUT];
    const int tid = threadIdx.x;
#pragma unroll
    for (int i = 0; i < KDIM * COUT / 1024; ++i) {
        const int idx = (i * 256 + tid) * 4;
        *(float4*)&Wl[idx] = *(const float4*)&W[idx];
    }
    __syncthreads();

    const int tx = tid % CT;
    const int ty = tid / CT;
    const int c0 = tx * 4;
    const int n0 = blockIdx.x * NT + ty * 4;

    const float4* xr[4];
#pragma unroll
    for (int nn = 0; nn < 4; ++nn) {
        const int node = n0 + nn;
        xr[nn] = (const float4*)(x + (size_t)(node < n_nodes ? node : 0) * KDIM);
    }

    float acc[4][4] = {};
#pragma unroll 4
    for (int k4 = 0; k4 < KDIM / 4; ++k4) {
        float4 xv[4], wv[4];
#pragma unroll
        for (int nn = 0; nn < 4; ++nn) xv[nn] = xr[nn][k4];
#pragma unroll
        for (int kk = 0; kk < 4; ++kk)
            wv[kk] = *(const float4*)&Wl[(k4 * 4 + kk) * COUT + c0];
#pragma unroll
        for (int nn = 0; nn < 4; ++nn) {
            const float xs0 = xv[nn].x, xs1 = xv[nn].y, xs2 = xv[nn].z, xs3 = xv[nn].w;
            acc[nn][0] = fmaf(xs0, wv[0].x, fmaf(xs1, wv[1].x, fmaf(xs2, wv[2].x, fmaf(xs3, wv[3].x, acc[nn][0]))));
            acc[nn][1] = fmaf(xs0, wv[0].y, fmaf(xs1, wv[1].y, fmaf(xs2, wv[2].y, fmaf(xs3, wv[3].y, acc[nn][1]))));
            acc[nn][2] = fmaf(xs0, wv[0].z, fmaf(xs1, wv[1].z, fmaf(xs2, wv[2].z, fmaf(xs3, wv[3].z, acc[nn][2]))));
            acc[nn][3] = fmaf(xs0, wv[0].w, fmaf(xs1, wv[1].w, fmaf(xs2, wv[2].w, fmaf(xs3, wv[3].w, acc[nn][3]))));
        }
    }

#pragma unroll
    for (int nn = 0; nn < 4; ++nn) {
        const int node = n0 + nn;
        if (node < n_nodes) {
            const float dv = dinv[node];
            float4 o;
            o.x = acc[nn][0] * dv; o.y = acc[nn][1] * dv;
            o.z = acc[nn][2] * dv; o.w = acc[nn][3] * dv;
            *(float4*)&g[(size_t)node * COUT + c0] = o;
        }
    }
}

__global__ void gemm3_kernel(const float* __restrict__ z2, const float* __restrict__ W3,
                             const float* __restrict__ dinv, float* __restrict__ g3, int n) {
    const int i = blockIdx.x * blockDim.x + threadIdx.x;
    if (i >= n) return;
    const float4* xr = (const float4*)(z2 + (size_t)i * 32);
    float acc = 0.0f;
#pragma unroll
    for (int k4 = 0; k4 < 8; ++k4) {
        const float4 xv = xr[k4];
        acc += xv.x * W3[4 * k4 + 0] + xv.y * W3[4 * k4 + 1] +
               xv.z * W3[4 * k4 + 2] + xv.w * W3[4 * k4 + 3];
    }
    g3[i] = acc * dinv[i];
}

// ---------------- fused CSR aggregation + finalize ----------------

__global__ __launch_bounds__(256) void agg_kernel64(
    const int* __restrict__ row_start, const int* __restrict__ esrc,
    const float* __restrict__ g, const float* __restrict__ dinv,
    const float* __restrict__ b, float* __restrict__ z, int n) {
    const int node = blockIdx.x * 4 + (threadIdx.x >> 6);
    if (node >= n) return;
    const int lane = threadIdx.x & 63;
    const int cg = lane & 15;
    const int es = lane >> 4;
    const float4* __restrict__ g4 = (const float4*)g;
    const int beg = row_start[node], end = row_start[node + 1];
    float4 a0 = {0, 0, 0, 0}, a1 = {0, 0, 0, 0};
    int e = beg;
    for (; e + 8 <= end; e += 8) {
        const int s0 = esrc[e + es];
        const int s1 = esrc[e + 4 + es];
        const float4 v0 = g4[(size_t)s0 * 16 + cg];
        const float4 v1 = g4[(size_t)s1 * 16 + cg];
        a0.x += v0.x; a0.y += v0.y; a0.z += v0.z; a0.w += v0.w;
        a1.x += v1.x; a1.y += v1.y; a1.z += v1.z; a1.w += v1.w;
    }
    for (; e < end; e += 4) {
        if (e + es < end) {
            const int s = esrc[e + es];
            const float4 v = g4[(size_t)s * 16 + cg];
            a0.x += v.x; a0.y += v.y; a0.z += v.z; a0.w += v.w;
        }
    }
    a0.x += a1.x; a0.y += a1.y; a0.z += a1.z; a0.w += a1.w;
    a0.x += __shfl_xor(a0.x, 16); a0.y += __shfl_xor(a0.y, 16);
    a0.z += __shfl_xor(a0.z, 16); a0.w += __shfl_xor(a0.w, 16);
    a0.x += __shfl_xor(a0.x, 32); a0.y += __shfl_xor(a0.y, 32);
    a0.z += __shfl_xor(a0.z, 32); a0.w += __shfl_xor(a0.w, 32);
    if (es == 0) {
        const float dv = dinv[node];
        const float4 gs = g4[(size_t)node * 16 + cg];
        const float4 bb = *(const float4*)&b[cg * 4];
        float4 o;
        o.x = fmaxf(dv * (a0.x + gs.x) + bb.x, 0.0f);
        o.y = fmaxf(dv * (a0.y + gs.y) + bb.y, 0.0f);
        o.z = fmaxf(dv * (a0.z + gs.z) + bb.z, 0.0f);
        o.w = fmaxf(dv * (a0.w + gs.w) + bb.w, 0.0f);
        ((float4*)z)[(size_t)node * 16 + cg] = o;
    }
}

__global__ __launch_bounds__(256) void agg_kernel32(
    const int* __restrict__ row_start, const int* __restrict__ esrc,
    const float* __restrict__ g, const float* __restrict__ dinv,
    const float* __restrict__ b, float* __restrict__ z, int n) {
    const int node = blockIdx.x * 4 + (threadIdx.x >> 6);
    if (node >= n) return;
    const int lane = threadIdx.x & 63;
    const int cg = lane & 7;
    const int es = lane >> 3;
    const float4* __restrict__ g4 = (const float4*)g;
    const int beg = row_start[node], end = row_start[node + 1];
    float4 a0 = {0, 0, 0, 0}, a1 = {0, 0, 0, 0};
    int e = beg;
    for (; e + 16 <= end; e += 16) {
        const int s0 = esrc[e + es];
        const int s1 = esrc[e + 8 + es];
        const float4 v0 = g4[(size_t)s0 * 8 + cg];
        const float4 v1 = g4[(size_t)s1 * 8 + cg];
        a0.x += v0.x; a0.y += v0.y; a0.z += v0.z; a0.w += v0.w;
        a1.x += v1.x; a1.y += v1.y; a1.z += v1.z; a1.w += v1.w;
    }
    for (; e < end; e += 8) {
        if (e + es < end) {
            const int s = esrc[e + es];
            const float4 v = g4[(size_t)s * 8 + cg];
            a0.x += v.x; a0.y += v.y; a0.z += v.z; a0.w += v.w;
        }
    }
    a0.x += a1.x; a0.y += a1.y; a0.z += a1.z; a0.w += a1.w;
#pragma unroll
    for (int m = 8; m < 64; m <<= 1) {
        a0.x += __shfl_xor(a0.x, m); a0.y += __shfl_xor(a0.y, m);
        a0.z += __shfl_xor(a0.z, m); a0.w += __shfl_xor(a0.w, m);
    }
    if (es == 0) {
        const float dv = dinv[node];
        const float4 gs = g4[(size_t)node * 8 + cg];
        const float4 bb = *(const float4*)&b[cg * 4];
        float4 o;
        o.x = fmaxf(dv * (a0.x + gs.x) + bb.x, 0.0f);
        o.y = fmaxf(dv * (a0.y + gs.y) + bb.y, 0.0f);
        o.z = fmaxf(dv * (a0.z + gs.z) + bb.z, 0.0f);
        o.w = fmaxf(dv * (a0.w + gs.w) + bb.w, 0.0f);
        ((float4*)z)[(size_t)node * 8 + cg] = o;
    }
}

__global__ __launch_bounds__(256) void agg_kernel1(
    const int* __restrict__ row_start, const int* __restrict__ esrc,
    const float* __restrict__ g, const float* __restrict__ dinv,
    const float* __restrict__ b3, float* __restrict__ out, int n) {
    const int node = blockIdx.x * 32 + (threadIdx.x >> 3);
    if (node >= n) return;
    const int l = threadIdx.x & 7;
    const int beg = row_start[node], end = row_start[node + 1];
    float acc = 0.0f;
    for (int e = beg + l; e < end; e += 8)
        acc += g[esrc[e]];
    acc += __shfl_xor(acc, 1);
    acc += __shfl_xor(acc, 2);
    acc += __shfl_xor(acc, 4);
    if (l == 0) out[node] = dinv[node] * (acc + g[node]) + b3[0];
}

// ---------------- launcher ----------------

extern "C" void kernel_launch(void* const* d_in, const int* in_sizes, int n_in,
                              void* d_out, int out_size, void* d_ws, size_t ws_size,
                              hipStream_t stream) {
    const float* x  = (const float*)d_in[0];
    const int*   ei = (const int*)d_in[1];
    const float* W1 = (const float*)d_in[2];
    const float* b1 = (const float*)d_in[3];
    const float* W2 = (const float*)d_in[4];
    const float* b2 = (const float*)d_in[5];
    const float* W3 = (const float*)d_in[6];
    const float* b3 = (const float*)d_in[7];
    float* out = (float*)d_out;

    const int n_nodes = in_sizes[0] / IN_C;    // 50000
    const int n_edges = in_sizes[1] / 2;       // 800000
    const int* src = ei;
    const int* dst = ei + n_edges;
    const int nb = (n_nodes + 255) / 256;            // scan blocks
    const int nbuckets = (n_nodes + (1 << NPB_SHIFT) - 1) >> NPB_SHIFT;  // 196

    auto align_up = [](size_t v) { return (v + 255) & ~(size_t)255; };
    char* p = (char*)d_ws;
    int*   cnt       = (int*)p;   p += align_up((size_t)n_nodes * 4);
    int*   partial   = (int*)p;   p += align_up(256 * 4);
    int*   bucketcur = (int*)p;   p += align_up(256 * 4);
    int*   row_start = (int*)p;   p += align_up(((size_t)n_nodes + 1) * 4);
    int*   esrc      = (int*)p;   p += align_up((size_t)n_edges * 4);
    int2*  tmp       = (int2*)p;  p += align_up((size_t)n_edges * 8);
    float* dinv      = (float*)p; p += align_up((size_t)n_nodes * 4);
    float* g1        = (float*)p; p += align_up((size_t)n_nodes * 64 * 4);
    float* z1        = (float*)p; p += align_up((size_t)n_nodes * 64 * 4);
    float* g2        = (float*)p; p += align_up((size_t)n_nodes * 32 * 4);
    float* z2        = (float*)p; p += align_up((size_t)n_nodes * 32 * 4);
    float* g3        = (float*)p; p += align_up((size_t)n_nodes * 4);
    (void)ws_size; (void)n_in; (void)out_size;

    hipMemsetAsync(cnt, 0, (size_t)n_nodes * 4, stream);

    // CSR build + normalization
    hist_kernel<<<2048, 256, 0, stream>>>(dst, cnt, n_edges);
    scan_partial_kernel<<<nb, 256, 0, stream>>>(cnt, partial, n_nodes);
    scan_mid_kernel<<<1, 256, 0, stream>>>(partial, nb);
    scan_final_kernel<<<nb, 256, 0, stream>>>(cnt, partial, row_start, dinv, bucketcur, n_nodes);
    partition_kernel<<<(n_edges + 2047) / 2048, 256, 0, stream>>>(src, dst, bucketcur, tmp, n_edges, nbuckets);
    local_fill_kernel<<<nbuckets, 256, 0, stream>>>(tmp, row_start, esrc, n_nodes, n_edges);

    // layer 1: 128 -> 64, relu
    gemm_tile_kernel<128, 64><<<(n_nodes + 63) / 64, 256, 0, stream>>>(x, W1, dinv, g1, n_nodes);
    agg_kernel64<<<(n_nodes + 3) / 4, 256, 0, stream>>>(row_start, esrc, g1, dinv, b1, z1, n_nodes);

    // layer 2: 64 -> 32, relu
    gemm_tile_kernel<64, 32><<<(n_nodes + 127) / 128, 256, 0, stream>>>(z1, W2, dinv, g2, n_nodes);
    agg_kernel32<<<(n_nodes + 3) / 4, 256, 0, stream>>>(row_start, esrc, g2, dinv, b2, z2, n_nodes);

    // layer 3: 32 -> 1
    gemm3_kernel<<<(n_nodes + 255) / 256, 256, 0, stream>>>(z2, W3, dinv, g3, n_nodes);
    agg_kernel1<<<(n_nodes + 31) / 32, 256, 0, stream>>>(row_start, esrc, g3, dinv, b3, out, n_nodes);
}

// Round 6
// 127.540 us; speedup vs baseline: 3.8241x; 1.3009x over previous
//
#include <hip/hip_runtime.h>

// StructuralGcn: 3-layer GCN, N=50000 nodes, E=800000 edges (+ self loops).
// Round 5 -> 6: top dispatch was the runtime's fillBufferAligned servicing
// hipMemsetAsync(cnt, 200KB) -- 40us at 0.4GB/s (tiny-grid latency-bound),
// feeding a hist+3-scan chain whose only job was row_start/dinv. Replaced
// global CSR with fixed-capacity per-bucket CSR (bucket = dst>>8, CAP=5120
// >> mean 4096 + 16 sigma): partition reserves via per-bucket atomics from 0;
// local_fill builds the 256-node histogram + scan in LDS and emits row_start
// (= b*CAP + local excl), deg, dinv directly. Kills the memset, hist_kernel,
// and all 3 scan kernels. tmp (dead after local_fill) overlays g2/z2/g3 to
// stay inside the prior workspace footprint.

#define IN_C 128
#define NPB_SHIFT 8            // 256 nodes per bucket
#define BCAP 5120              // per-bucket edge capacity (mean 4096, sd ~64)

// ---------------- tiny init ----------------

__global__ void zero256_kernel(int* __restrict__ p) { p[threadIdx.x] = 0; }

// ---------------- pass 1: block-local counting sort by bucket ----------------
// Coalesced run-writes of (dst,src) into per-bucket fixed regions reserved via
// one global atomic per (block, bucket).

__global__ __launch_bounds__(256) void partition_kernel(
    const int* __restrict__ src, const int* __restrict__ dst,
    int* __restrict__ bucketcur, int2* __restrict__ tmp, int n_edges, int nb) {
    constexpr int EPT = 8;                 // edges per thread
    __shared__ int hist[256];
    __shared__ int excl[256];
    __shared__ int rankc[256];
    __shared__ int gbase[256];
    __shared__ int2 sorted[256 * EPT];     // 16 KB

    const int t = threadIdx.x;
    const int e0 = blockIdx.x * 256 * EPT;
    hist[t] = 0;
    rankc[t] = 0;
    __syncthreads();

    int d[EPT], s[EPT];
#pragma unroll
    for (int i = 0; i < EPT; ++i) {
        const int e = e0 + t + i * 256;    // coalesced
        if (e < n_edges) {
            d[i] = dst[e];
            s[i] = src[e];
            atomicAdd(&hist[d[i] >> NPB_SHIFT], 1);
        } else {
            d[i] = -1;
        }
    }
    __syncthreads();

    const int hv = hist[t];
    excl[t] = hv;
    __syncthreads();
    for (int off = 1; off < 256; off <<= 1) {
        const int u = (t >= off) ? excl[t - off] : 0;
        __syncthreads();
        excl[t] += u;
        __syncthreads();
    }
    const int ex = excl[t] - hv;
    __syncthreads();
    excl[t] = ex;
    if (t < nb && hv > 0) gbase[t] = t * BCAP + atomicAdd(&bucketcur[t], hv);
    __syncthreads();

    // scatter into LDS in bucket-sorted order
#pragma unroll
    for (int i = 0; i < EPT; ++i) {
        if (d[i] >= 0) {
            const int b = d[i] >> NPB_SHIFT;
            const int r = atomicAdd(&rankc[b], 1);
            sorted[excl[b] + r] = make_int2(d[i], s[i]);
        }
    }
    __syncthreads();

    // coalesced run-writes to global bucket regions
    const int m = min(256 * EPT, n_edges - e0);
    for (int i = t; i < m; i += 256) {
        const int2 p = sorted[i];
        const int b = p.x >> NPB_SHIFT;
        tmp[gbase[b] + (i - excl[b])] = p;
    }
}

// ---------------- pass 2: per-bucket CSR build + fill ----------------
// One block per bucket: LDS histogram of the bucket's 256 nodes, LDS scan ->
// row_start/deg/dinv, then rank edges into esrc via LDS cursors.

__global__ __launch_bounds__(256) void local_fill_kernel(
    const int2* __restrict__ tmp, const int* __restrict__ bucketcur,
    int* __restrict__ row_start, int* __restrict__ deg, float* __restrict__ dinv,
    int* __restrict__ esrc, int n_nodes) {
    __shared__ int histl[256];
    __shared__ int excl[256];
    __shared__ int cur[256];
    const int b = blockIdx.x;
    const int base = b * BCAP;
    const int t = threadIdx.x;
    const int m = bucketcur[b];
    histl[t] = 0;
    __syncthreads();

    for (int i = t; i < m; i += 256)
        atomicAdd(&histl[tmp[base + i].x & 255], 1);
    __syncthreads();

    const int hv = histl[t];
    excl[t] = hv;
    __syncthreads();
    for (int off = 1; off < 256; off <<= 1) {
        const int u = (t >= off) ? excl[t - off] : 0;
        __syncthreads();
        excl[t] += u;
        __syncthreads();
    }
    const int rs = base + excl[t] - hv;
    const int node = (b << NPB_SHIFT) + t;
    if (node < n_nodes) {
        row_start[node] = rs;
        deg[node] = hv;
        dinv[node] = rsqrtf((float)hv + 1.0f);   // +1 = self loop
    }
    cur[t] = rs;
    __syncthreads();

    for (int i = t; i < m; i += 256) {
        const int2 p = tmp[base + i];
        const int pos = atomicAdd(&cur[p.x & 255], 1);
        esrc[pos] = p.y;
    }
}

// ---------------- register-blocked GEMM with dinv epilogue ----------------

template <int KDIM, int COUT>
__global__ __launch_bounds__(256) void gemm_tile_kernel(
    const float* __restrict__ x, const float* __restrict__ W,
    const float* __restrict__ dinv, float* __restrict__ g, int n_nodes) {
    constexpr int CT = COUT / 4;
    constexpr int NG = 256 / CT;
    constexpr int NT = NG * 4;

    __shared__ float Wl[KDIM * COUT];
    const int tid = threadIdx.x;
#pragma unroll
    for (int i = 0; i < KDIM * COUT / 1024; ++i) {
        const int idx = (i * 256 + tid) * 4;
        *(float4*)&Wl[idx] = *(const float4*)&W[idx];
    }
    __syncthreads();

    const int tx = tid % CT;
    const int ty = tid / CT;
    const int c0 = tx * 4;
    const int n0 = blockIdx.x * NT + ty * 4;

    const float4* xr[4];
#pragma unroll
    for (int nn = 0; nn < 4; ++nn) {
        const int node = n0 + nn;
        xr[nn] = (const float4*)(x + (size_t)(node < n_nodes ? node : 0) * KDIM);
    }

    float acc[4][4] = {};
#pragma unroll 4
    for (int k4 = 0; k4 < KDIM / 4; ++k4) {
        float4 xv[4], wv[4];
#pragma unroll
        for (int nn = 0; nn < 4; ++nn) xv[nn] = xr[nn][k4];
#pragma unroll
        for (int kk = 0; kk < 4; ++kk)
            wv[kk] = *(const float4*)&Wl[(k4 * 4 + kk) * COUT + c0];
#pragma unroll
        for (int nn = 0; nn < 4; ++nn) {
            const float xs0 = xv[nn].x, xs1 = xv[nn].y, xs2 = xv[nn].z, xs3 = xv[nn].w;
            acc[nn][0] = fmaf(xs0, wv[0].x, fmaf(xs1, wv[1].x, fmaf(xs2, wv[2].x, fmaf(xs3, wv[3].x, acc[nn][0]))));
            acc[nn][1] = fmaf(xs0, wv[0].y, fmaf(xs1, wv[1].y, fmaf(xs2, wv[2].y, fmaf(xs3, wv[3].y, acc[nn][1]))));
            acc[nn][2] = fmaf(xs0, wv[0].z, fmaf(xs1, wv[1].z, fmaf(xs2, wv[2].z, fmaf(xs3, wv[3].z, acc[nn][2]))));
            acc[nn][3] = fmaf(xs0, wv[0].w, fmaf(xs1, wv[1].w, fmaf(xs2, wv[2].w, fmaf(xs3, wv[3].w, acc[nn][3]))));
        }
    }

#pragma unroll
    for (int nn = 0; nn < 4; ++nn) {
        const int node = n0 + nn;
        if (node < n_nodes) {
            const float dv = dinv[node];
            float4 o;
            o.x = acc[nn][0] * dv; o.y = acc[nn][1] * dv;
            o.z = acc[nn][2] * dv; o.w = acc[nn][3] * dv;
            *(float4*)&g[(size_t)node * COUT + c0] = o;
        }
    }
}

__global__ void gemm3_kernel(const float* __restrict__ z2, const float* __restrict__ W3,
                             const float* __restrict__ dinv, float* __restrict__ g3, int n) {
    const int i = blockIdx.x * blockDim.x + threadIdx.x;
    if (i >= n) return;
    const float4* xr = (const float4*)(z2 + (size_t)i * 32);
    float acc = 0.0f;
#pragma unroll
    for (int k4 = 0; k4 < 8; ++k4) {
        const float4 xv = xr[k4];
        acc += xv.x * W3[4 * k4 + 0] + xv.y * W3[4 * k4 + 1] +
               xv.z * W3[4 * k4 + 2] + xv.w * W3[4 * k4 + 3];
    }
    g3[i] = acc * dinv[i];
}

// ---------------- fused CSR aggregation + finalize ----------------

__global__ __launch_bounds__(256) void agg_kernel64(
    const int* __restrict__ row_start, const int* __restrict__ deg,
    const int* __restrict__ esrc, const float* __restrict__ g,
    const float* __restrict__ dinv, const float* __restrict__ b,
    float* __restrict__ z, int n) {
    const int node = blockIdx.x * 4 + (threadIdx.x >> 6);
    if (node >= n) return;
    const int lane = threadIdx.x & 63;
    const int cg = lane & 15;
    const int es = lane >> 4;
    const float4* __restrict__ g4 = (const float4*)g;
    const int beg = row_start[node], end = beg + deg[node];
    float4 a0 = {0, 0, 0, 0}, a1 = {0, 0, 0, 0};
    int e = beg;
    for (; e + 8 <= end; e += 8) {
        const int s0 = esrc[e + es];
        const int s1 = esrc[e + 4 + es];
        const float4 v0 = g4[(size_t)s0 * 16 + cg];
        const float4 v1 = g4[(size_t)s1 * 16 + cg];
        a0.x += v0.x; a0.y += v0.y; a0.z += v0.z; a0.w += v0.w;
        a1.x += v1.x; a1.y += v1.y; a1.z += v1.z; a1.w += v1.w;
    }
    for (; e < end; e += 4) {
        if (e + es < end) {
            const int s = esrc[e + es];
            const float4 v = g4[(size_t)s * 16 + cg];
            a0.x += v.x; a0.y += v.y; a0.z += v.z; a0.w += v.w;
        }
    }
    a0.x += a1.x; a0.y += a1.y; a0.z += a1.z; a0.w += a1.w;
    a0.x += __shfl_xor(a0.x, 16); a0.y += __shfl_xor(a0.y, 16);
    a0.z += __shfl_xor(a0.z, 16); a0.w += __shfl_xor(a0.w, 16);
    a0.x += __shfl_xor(a0.x, 32); a0.y += __shfl_xor(a0.y, 32);
    a0.z += __shfl_xor(a0.z, 32); a0.w += __shfl_xor(a0.w, 32);
    if (es == 0) {
        const float dv = dinv[node];
        const float4 gs = g4[(size_t)node * 16 + cg];
        const float4 bb = *(const float4*)&b[cg * 4];
        float4 o;
        o.x = fmaxf(dv * (a0.x + gs.x) + bb.x, 0.0f);
        o.y = fmaxf(dv * (a0.y + gs.y) + bb.y, 0.0f);
        o.z = fmaxf(dv * (a0.z + gs.z) + bb.z, 0.0f);
        o.w = fmaxf(dv * (a0.w + gs.w) + bb.w, 0.0f);
        ((float4*)z)[(size_t)node * 16 + cg] = o;
    }
}

__global__ __launch_bounds__(256) void agg_kernel32(
    const int* __restrict__ row_start, const int* __restrict__ deg,
    const int* __restrict__ esrc, const float* __restrict__ g,
    const float* __restrict__ dinv, const float* __restrict__ b,
    float* __restrict__ z, int n) {
    const int node = blockIdx.x * 4 + (threadIdx.x >> 6);
    if (node >= n) return;
    const int lane = threadIdx.x & 63;
    const int cg = lane & 7;
    const int es = lane >> 3;
    const float4* __restrict__ g4 = (const float4*)g;
    const int beg = row_start[node], end = beg + deg[node];
    float4 a0 = {0, 0, 0, 0}, a1 = {0, 0, 0, 0};
    int e = beg;
    for (; e + 16 <= end; e += 16) {
        const int s0 = esrc[e + es];
        const int s1 = esrc[e + 8 + es];
        const float4 v0 = g4[(size_t)s0 * 8 + cg];
        const float4 v1 = g4[(size_t)s1 * 8 + cg];
        a0.x += v0.x; a0.y += v0.y; a0.z += v0.z; a0.w += v0.w;
        a1.x += v1.x; a1.y += v1.y; a1.z += v1.z; a1.w += v1.w;
    }
    for (; e < end; e += 8) {
        if (e + es < end) {
            const int s = esrc[e + es];
            const float4 v = g4[(size_t)s * 8 + cg];
            a0.x += v.x; a0.y += v.y; a0.z += v.z; a0.w += v.w;
        }
    }
    a0.x += a1.x; a0.y += a1.y; a0.z += a1.z; a0.w += a1.w;
#pragma unroll
    for (int m = 8; m < 64; m <<= 1) {
        a0.x += __shfl_xor(a0.x, m); a0.y += __shfl_xor(a0.y, m);
        a0.z += __shfl_xor(a0.z, m); a0.w += __shfl_xor(a0.w, m);
    }
    if (es == 0) {
        const float dv = dinv[node];
        const float4 gs = g4[(size_t)node * 8 + cg];
        const float4 bb = *(const float4*)&b[cg * 4];
        float4 o;
        o.x = fmaxf(dv * (a0.x + gs.x) + bb.x, 0.0f);
        o.y = fmaxf(dv * (a0.y + gs.y) + bb.y, 0.0f);
        o.z = fmaxf(dv * (a0.z + gs.z) + bb.z, 0.0f);
        o.w = fmaxf(dv * (a0.w + gs.w) + bb.w, 0.0f);
        ((float4*)z)[(size_t)node * 8 + cg] = o;
    }
}

__global__ __launch_bounds__(256) void agg_kernel1(
    const int* __restrict__ row_start, const int* __restrict__ deg,
    const int* __restrict__ esrc, const float* __restrict__ g,
    const float* __restrict__ dinv, const float* __restrict__ b3,
    float* __restrict__ out, int n) {
    const int node = blockIdx.x * 32 + (threadIdx.x >> 3);
    if (node >= n) return;
    const int l = threadIdx.x & 7;
    const int beg = row_start[node], end = beg + deg[node];
    float acc = 0.0f;
    for (int e = beg + l; e < end; e += 8)
        acc += g[esrc[e]];
    acc += __shfl_xor(acc, 1);
    acc += __shfl_xor(acc, 2);
    acc += __shfl_xor(acc, 4);
    if (l == 0) out[node] = dinv[node] * (acc + g[node]) + b3[0];
}

// ---------------- launcher ----------------

extern "C" void kernel_launch(void* const* d_in, const int* in_sizes, int n_in,
                              void* d_out, int out_size, void* d_ws, size_t ws_size,
                              hipStream_t stream) {
    const float* x  = (const float*)d_in[0];
    const int*   ei = (const int*)d_in[1];
    const float* W1 = (const float*)d_in[2];
    const float* b1 = (const float*)d_in[3];
    const float* W2 = (const float*)d_in[4];
    const float* b2 = (const float*)d_in[5];
    const float* W3 = (const float*)d_in[6];
    const float* b3 = (const float*)d_in[7];
    float* out = (float*)d_out;

    const int n_nodes = in_sizes[0] / IN_C;    // 50000
    const int n_edges = in_sizes[1] / 2;       // 800000
    const int* src = ei;
    const int* dst = ei + n_edges;
    const int nbuckets = (n_nodes + (1 << NPB_SHIFT) - 1) >> NPB_SHIFT;  // 196

    auto align_up = [](size_t v) { return (v + 255) & ~(size_t)255; };
    char* p = (char*)d_ws;
    int*   bucketcur = (int*)p;   p += align_up(256 * 4);
    int*   row_start = (int*)p;   p += align_up((size_t)n_nodes * 4);
    int*   deg       = (int*)p;   p += align_up((size_t)n_nodes * 4);
    float* dinv      = (float*)p; p += align_up((size_t)n_nodes * 4);
    int*   esrc      = (int*)p;   p += align_up((size_t)nbuckets * BCAP * 4);
    float* g1        = (float*)p; p += align_up((size_t)n_nodes * 64 * 4);
    float* z1        = (float*)p; p += align_up((size_t)n_nodes * 64 * 4);
    // union region: tmp (partition/local_fill only) overlaid by g2/z2/g3
    char*  up = p;
    int2*  tmp       = (int2*)up;                 // nbuckets*BCAP*8 = 8.0 MB
    float* g2        = (float*)up;                // 6.4 MB
    float* z2        = (float*)(up + align_up((size_t)n_nodes * 32 * 4));
    float* g3        = (float*)(up + 2 * align_up((size_t)n_nodes * 32 * 4));
    (void)ws_size; (void)n_in; (void)out_size;

    // CSR build (bucketed, no global scan)
    zero256_kernel<<<1, 256, 0, stream>>>(bucketcur);
    partition_kernel<<<(n_edges + 2047) / 2048, 256, 0, stream>>>(src, dst, bucketcur, tmp, n_edges, nbuckets);
    local_fill_kernel<<<nbuckets, 256, 0, stream>>>(tmp, bucketcur, row_start, deg, dinv, esrc, n_nodes);

    // layer 1: 128 -> 64, relu
    gemm_tile_kernel<128, 64><<<(n_nodes + 63) / 64, 256, 0, stream>>>(x, W1, dinv, g1, n_nodes);
    agg_kernel64<<<(n_nodes + 3) / 4, 256, 0, stream>>>(row_start, deg, esrc, g1, dinv, b1, z1, n_nodes);

    // layer 2: 64 -> 32, relu
    gemm_tile_kernel<64, 32><<<(n_nodes + 127) / 128, 256, 0, stream>>>(z1, W2, dinv, g2, n_nodes);
    agg_kernel32<<<(n_nodes + 3) / 4, 256, 0, stream>>>(row_start, deg, esrc, g2, dinv, b2, z2, n_nodes);

    // layer 3: 32 -> 1
    gemm3_kernel<<<(n_nodes + 255) / 256, 256, 0, stream>>>(z2, W3, dinv, g3, n_nodes);
    agg_kernel1<<<(n_nodes + 31) / 32, 256, 0, stream>>>(row_start, deg, esrc, g3, dinv, b3, out, n_nodes);
}